// Round 1
// baseline (252.890 us; speedup 1.0000x reference)
//
#include <hip/hip_runtime.h>
#include <hip/hip_fp16.h>

#define BB 4
#define CC 256
#define CQ 32
#define NN 4096   // 64*64

// ---------------------------------------------------------------------------
// K1: Q/K projections.  q[b,o,n] = sum_c wq[o,c] x[b,c,n] + bq[o]
// grid (N/256, 8, B); groups 0..3 -> Q rows 0..31, groups 4..7 -> K rows 0..31
// ---------------------------------------------------------------------------
__global__ __launch_bounds__(256) void qk_proj_kernel(
    const float* __restrict__ x,
    const float* __restrict__ wq, const float* __restrict__ bq,
    const float* __restrict__ wk, const float* __restrict__ bk,
    float* __restrict__ Qb, float* __restrict__ Kb)
{
    const int n   = blockIdx.x * 256 + threadIdx.x;
    const int grp = blockIdx.y;
    const int b   = blockIdx.z;

    const float* w; const float* bias; float* dst; int o0;
    if (grp < 4) { w = wq; bias = bq; dst = Qb; o0 = grp * 8; }
    else         { w = wk; bias = bk; dst = Kb; o0 = (grp - 4) * 8; }

    const float* wr[8];
    float bb2[8];
    #pragma unroll
    for (int u = 0; u < 8; ++u) { wr[u] = w + (size_t)(o0 + u) * CC; bb2[u] = bias[o0 + u]; }

    float acc[8];
    #pragma unroll
    for (int u = 0; u < 8; ++u) acc[u] = 0.f;

    const float* xp = x + (size_t)b * CC * NN + n;
    #pragma unroll 4
    for (int c = 0; c < CC; ++c) {
        float xv = xp[(size_t)c * NN];
        #pragma unroll
        for (int u = 0; u < 8; ++u) acc[u] += wr[u][c] * xv;
    }
    #pragma unroll
    for (int u = 0; u < 8; ++u)
        dst[((size_t)b * CQ + o0 + u) * NN + n] = acc[u] + bb2[u];
}

// ---------------------------------------------------------------------------
// K2: V projection -> transposed layout Vt[b][n][c]  (gamma-guarded)
// grid (N/256, C/8, B)
// ---------------------------------------------------------------------------
__global__ __launch_bounds__(256) void v_proj_kernel(
    const float* __restrict__ x,
    const float* __restrict__ wv, const float* __restrict__ bv,
    const float* __restrict__ gamma,
    float* __restrict__ Vt)
{
    if (gamma[0] == 0.f) return;
    const int n  = blockIdx.x * 256 + threadIdx.x;
    const int c0 = blockIdx.y * 8;
    const int b  = blockIdx.z;

    const float* wr[8];
    float bb2[8];
    #pragma unroll
    for (int u = 0; u < 8; ++u) { wr[u] = wv + (size_t)(c0 + u) * CC; bb2[u] = bv[c0 + u]; }

    float acc[8];
    #pragma unroll
    for (int u = 0; u < 8; ++u) acc[u] = 0.f;

    const float* xp = x + (size_t)b * CC * NN + n;
    #pragma unroll 4
    for (int c = 0; c < CC; ++c) {
        float xv = xp[(size_t)c * NN];
        #pragma unroll
        for (int u = 0; u < 8; ++u) acc[u] += wr[u][c] * xv;
    }
    #pragma unroll
    for (int u = 0; u < 8; ++u)
        Vt[((size_t)b * NN + n) * CC + c0 + u] = acc[u] + bb2[u];
}

// ---------------------------------------------------------------------------
// K3: fused energy + softmax + attention write.
// Block = 8 query rows (one wave per row), 512 threads.
// LDS: K tile [32][256] f32 (32 KB) + e rows [8][4096] fp16 (64 KB) = 96 KB.
// ---------------------------------------------------------------------------
__global__ __launch_bounds__(512) void attn_kernel(
    const float* __restrict__ Qb, const float* __restrict__ Kb,
    float* __restrict__ att)
{
    __shared__ float ks[CQ][256];
    __shared__ __align__(16) __half es[8][NN];

    const int tid  = threadIdx.x;
    const int w    = tid >> 6;
    const int lane = tid & 63;
    const int b    = blockIdx.y;
    const int r    = blockIdx.x * 8 + w;   // query row

    // preload q row (uniform per wave -> broadcast loads, kept in VGPRs)
    float qv[CQ];
    const float* qp = Qb + (size_t)b * CQ * NN + r;
    #pragma unroll
    for (int cq = 0; cq < CQ; ++cq) qv[cq] = qp[(size_t)cq * NN];

    const float* kbase = Kb + (size_t)b * CQ * NN;
    const int jj = lane * 4;

    for (int t = 0; t < NN / 256; ++t) {
        __syncthreads();
        // stage K tile: 8192 floats, 512 threads * 4 float4
        #pragma unroll
        for (int it = 0; it < 4; ++it) {
            int idx = (it * 512 + tid) * 4;
            int cq  = idx >> 8;
            int j0  = idx & 255;
            float4 kv = *reinterpret_cast<const float4*>(kbase + (size_t)cq * NN + t * 256 + j0);
            *reinterpret_cast<float4*>(&ks[cq][j0]) = kv;
        }
        __syncthreads();

        float4 acc = make_float4(0.f, 0.f, 0.f, 0.f);
        #pragma unroll
        for (int cq = 0; cq < CQ; ++cq) {
            float4 kv = *reinterpret_cast<const float4*>(&ks[cq][jj]);
            acc.x += qv[cq] * kv.x;
            acc.y += qv[cq] * kv.y;
            acc.z += qv[cq] * kv.z;
            acc.w += qv[cq] * kv.w;
        }
        __half2 h01; h01.x = __float2half_rn(acc.x); h01.y = __float2half_rn(acc.y);
        __half2 h23; h23.x = __float2half_rn(acc.z); h23.y = __float2half_rn(acc.w);
        __half2* ep = reinterpret_cast<__half2*>(&es[w][t * 256 + jj]);
        ep[0] = h01;
        ep[1] = h23;
    }

    // ---- per-wave softmax over row r (wave w only touches es[w]) ----
    float m = -1e30f;
    #pragma unroll 4
    for (int t = 0; t < 16; ++t) {
        const __half2* ep = reinterpret_cast<const __half2*>(&es[w][t * 256 + jj]);
        __half2 h01 = ep[0], h23 = ep[1];
        m = fmaxf(m, fmaxf(fmaxf(__half2float(h01.x), __half2float(h01.y)),
                           fmaxf(__half2float(h23.x), __half2float(h23.y))));
    }
    #pragma unroll
    for (int off = 32; off >= 1; off >>= 1) m = fmaxf(m, __shfl_xor(m, off, 64));

    float s = 0.f;
    #pragma unroll 4
    for (int t = 0; t < 16; ++t) {
        const __half2* ep = reinterpret_cast<const __half2*>(&es[w][t * 256 + jj]);
        __half2 h01 = ep[0], h23 = ep[1];
        s += __expf(__half2float(h01.x) - m) + __expf(__half2float(h01.y) - m)
           + __expf(__half2float(h23.x) - m) + __expf(__half2float(h23.y) - m);
    }
    #pragma unroll
    for (int off = 32; off >= 1; off >>= 1) s += __shfl_xor(s, off, 64);
    const float inv = 1.f / s;

    float* arow = att + ((size_t)b * NN + r) * NN;
    #pragma unroll 2
    for (int t = 0; t < 16; ++t) {
        const __half2* ep = reinterpret_cast<const __half2*>(&es[w][t * 256 + jj]);
        __half2 h01 = ep[0], h23 = ep[1];
        float4 o;
        o.x = __expf(__half2float(h01.x) - m) * inv;
        o.y = __expf(__half2float(h01.y) - m) * inv;
        o.z = __expf(__half2float(h23.x) - m) * inv;
        o.w = __expf(__half2float(h23.y) - m) * inv;
        *reinterpret_cast<float4*>(&arow[t * 256 + jj]) = o;
    }
}

// ---------------------------------------------------------------------------
// K4: PV (gamma-guarded; never runs when gamma==0).  Pt[b][i][c].
// ---------------------------------------------------------------------------
__global__ __launch_bounds__(256) void pv_kernel(
    const float* __restrict__ att, const float* __restrict__ Vt,
    const float* __restrict__ gamma, float* __restrict__ Pt)
{
    if (gamma[0] == 0.f) return;
    const size_t idx = (size_t)blockIdx.x * 256 + threadIdx.x;  // over B*N*C
    const int c = (int)(idx % CC);
    const size_t bn = idx / CC;
    const int i = (int)(bn % NN);
    const int b = (int)(bn / NN);

    const float* arow = att + ((size_t)b * NN + i) * NN;
    const float* vcol = Vt + (size_t)b * NN * CC + c;
    float acc = 0.f;
    for (int j = 0; j < NN; ++j) acc += arow[j] * vcol[(size_t)j * CC];
    Pt[idx] = acc;
}

// ---------------------------------------------------------------------------
// K5: out = gamma * PV + x   (when gamma==0: exact copy of x)
// ---------------------------------------------------------------------------
__global__ __launch_bounds__(256) void out_kernel(
    const float* __restrict__ x, const float* __restrict__ Pt,
    const float* __restrict__ gamma, float* __restrict__ out)
{
    const size_t idx = (size_t)blockIdx.x * 256 + threadIdx.x;  // over B*C*N
    const float g = gamma[0];
    float v = x[idx];
    if (g != 0.f) {
        const int n = (int)(idx % NN);
        const size_t bc = idx / NN;
        const int c = (int)(bc % CC);
        const int b = (int)(bc / CC);
        v += g * Pt[((size_t)b * NN + n) * CC + c];
    }
    out[idx] = v;
}

extern "C" void kernel_launch(void* const* d_in, const int* in_sizes, int n_in,
                              void* d_out, int out_size, void* d_ws, size_t ws_size,
                              hipStream_t stream)
{
    const float* x     = (const float*)d_in[0];
    const float* wq    = (const float*)d_in[1];
    const float* bq    = (const float*)d_in[2];
    const float* wk    = (const float*)d_in[3];
    const float* bk    = (const float*)d_in[4];
    const float* wv    = (const float*)d_in[5];
    const float* bv    = (const float*)d_in[6];
    const float* gamma = (const float*)d_in[7];

    float* out = (float*)d_out;                    // [B,C,W,H] = B*C*N
    float* att = out + (size_t)BB * CC * NN;       // [B,N,N]

    float* Qb = (float*)d_ws;                      // B*CQ*N
    float* Kb = Qb + (size_t)BB * CQ * NN;         // B*CQ*N
    float* Vt = Kb + (size_t)BB * CQ * NN;         // B*N*C
    float* Pt = Vt + (size_t)BB * NN * CC;         // B*N*C

    qk_proj_kernel<<<dim3(NN / 256, 8, BB), 256, 0, stream>>>(x, wq, bq, wk, bk, Qb, Kb);
    v_proj_kernel<<<dim3(NN / 256, CC / 8, BB), 256, 0, stream>>>(x, wv, bv, gamma, Vt);
    attn_kernel<<<dim3(NN / 8, BB), 512, 0, stream>>>(Qb, Kb, att);
    pv_kernel<<<dim3((BB * NN * CC) / 256), 256, 0, stream>>>(att, Vt, gamma, Pt);
    out_kernel<<<dim3((BB * CC * NN) / 256), 256, 0, stream>>>(x, Pt, gamma, out);
}

// Round 2
// 140.215 us; speedup vs baseline: 1.8036x; 1.8036x over previous
//
#include <hip/hip_runtime.h>

#define BB 4
#define CC 256
#define CQ 32
#define NN 4096   // 64*64

typedef __attribute__((ext_vector_type(8))) short bf16x8;
typedef __attribute__((ext_vector_type(16))) float f32x16;

__device__ __forceinline__ unsigned short f2bf(float f) {
    unsigned int u = __float_as_uint(f);
    unsigned int r = (u + 0x7fffu + ((u >> 16) & 1u)) >> 16;
    return (unsigned short)r;
}

// ---------------------------------------------------------------------------
// K1: Q/K projections -> transposed bf16 buffers for MFMA.
//   Qtb[b][n][cq]  (linear chunks)
//   Ktb[b][n][cq]  (8-cq chunks XOR-swizzled: chunk c stored at pos c^(n&3))
// grid (NN/128, 4, BB), block 128. grp 0,1 = Q halves; 2,3 = K halves.
// ---------------------------------------------------------------------------
__global__ __launch_bounds__(128) void qk_proj_kernel(
    const float* __restrict__ x,
    const float* __restrict__ wq, const float* __restrict__ bq,
    const float* __restrict__ wk, const float* __restrict__ bk,
    unsigned short* __restrict__ Qtb, unsigned short* __restrict__ Ktb)
{
    const int n   = blockIdx.x * 128 + threadIdx.x;
    const int grp = blockIdx.y;
    const int b   = blockIdx.z;
    const bool isQ = (grp < 2);
    const int o0 = (grp & 1) * 16;

    const float* w    = isQ ? wq : wk;
    const float* bias = isQ ? bq : bk;

    float acc[16];
    #pragma unroll
    for (int u = 0; u < 16; ++u) acc[u] = bias[o0 + u];

    const float* xp = x + (size_t)b * CC * NN + n;
    const float* wp = w + (size_t)o0 * CC;
    #pragma unroll 4
    for (int c = 0; c < CC; ++c) {
        float xv = xp[(size_t)c * NN];
        #pragma unroll
        for (int u = 0; u < 16; ++u) acc[u] += wp[u * CC + c] * xv;
    }

    // pack to bf16: 4 dwords per 8 outputs
    unsigned int pk[8];
    #pragma unroll
    for (int j = 0; j < 8; ++j)
        pk[j] = (unsigned int)f2bf(acc[2 * j]) | ((unsigned int)f2bf(acc[2 * j + 1]) << 16);
    uint4 lo = make_uint4(pk[0], pk[1], pk[2], pk[3]);
    uint4 hi = make_uint4(pk[4], pk[5], pk[6], pk[7]);

    if (isQ) {
        unsigned short* dst = Qtb + ((size_t)b * NN + n) * CQ;
        *reinterpret_cast<uint4*>(dst + o0)     = lo;
        *reinterpret_cast<uint4*>(dst + o0 + 8) = hi;
    } else {
        unsigned short* dst = Ktb + ((size_t)b * NN + n) * CQ;
        const int c0 = o0 >> 3;                 // logical chunk (8 cq each)
        const int p0 = (c0    ) ^ (n & 3);      // swizzled position
        const int p1 = (c0 + 1) ^ (n & 3);
        *reinterpret_cast<uint4*>(dst + p0 * 8) = lo;
        *reinterpret_cast<uint4*>(dst + p1 * 8) = hi;
    }
}

// ---------------------------------------------------------------------------
// K2: V projection -> Vt[b][n][c]  (gamma-guarded; skipped when gamma==0)
// ---------------------------------------------------------------------------
__global__ __launch_bounds__(256) void v_proj_kernel(
    const float* __restrict__ x,
    const float* __restrict__ wv, const float* __restrict__ bv,
    const float* __restrict__ gamma,
    float* __restrict__ Vt)
{
    if (gamma[0] == 0.f) return;
    const int n  = blockIdx.x * 256 + threadIdx.x;
    const int c0 = blockIdx.y * 8;
    const int b  = blockIdx.z;

    const float* wr[8];
    float bb2[8];
    #pragma unroll
    for (int u = 0; u < 8; ++u) { wr[u] = wv + (size_t)(c0 + u) * CC; bb2[u] = bv[c0 + u]; }

    float acc[8];
    #pragma unroll
    for (int u = 0; u < 8; ++u) acc[u] = 0.f;

    const float* xp = x + (size_t)b * CC * NN + n;
    #pragma unroll 4
    for (int c = 0; c < CC; ++c) {
        float xv = xp[(size_t)c * NN];
        #pragma unroll
        for (int u = 0; u < 8; ++u) acc[u] += wr[u][c] * xv;
    }
    #pragma unroll
    for (int u = 0; u < 8; ++u)
        Vt[((size_t)b * NN + n) * CC + c0 + u] = acc[u] + bb2[u];
}

// ---------------------------------------------------------------------------
// K3: MFMA energy + 3-pass softmax (max / sum / normalize+write).
// Block = 32 query rows x 4096 cols, 8 waves (512 thr). Each wave owns 128
// cols per 1024-col K tile. K tile staged in LDS (64 KB, swizzled layout so
// ds_read_b128 B-frags are conflict-free). Energy is recomputed per pass
// (MFMA is cheap); only m/s per row are kept between passes.
// C-frag layout (m101-verified): col=lane&31, row=(reg&3)+8*(reg>>2)+4*(lane>>5)
// ---------------------------------------------------------------------------
__global__ __launch_bounds__(512, 4) void attn_kernel(
    const unsigned short* __restrict__ Qtb,
    const unsigned short* __restrict__ Ktb,
    float* __restrict__ att)
{
    __shared__ __align__(16) unsigned short kt[1024 * CQ];  // 64 KB
    __shared__ float red[8][32];
    __shared__ float rowv[32];

    const int tid  = threadIdx.x;
    const int w    = tid >> 6;
    const int lane = tid & 63;
    const int l31  = lane & 31;
    const int h    = lane >> 5;
    const int b    = blockIdx.y;
    const int i0   = blockIdx.x * 32;

    // A-frags: Q rows i0..i0+31, lane l: row=l&31, k-chunk = (l>>5)+2m (8 contiguous cq)
    const unsigned short* qb = Qtb + ((size_t)b * NN + i0) * CQ + (size_t)l31 * CQ;
    const bf16x8 a0 = *reinterpret_cast<const bf16x8*>(qb + h * 8);
    const bf16x8 a1 = *reinterpret_cast<const bf16x8*>(qb + (h + 2) * 8);

    // staging: linear copy (source pre-swizzled by producer), 8 KB per wave
    const char* ksrc = reinterpret_cast<const char*>(Ktb + (size_t)b * NN * CQ) + w * 8192 + lane * 16;
    char* kdst = reinterpret_cast<char*>(kt) + w * 8192 + lane * 16;
    const char* ktc = reinterpret_cast<const char*>(kt);

    // B-frag byte offsets in kt: j = w*128 + s*32 + l31, chunk c=(h)+2m at pos c^(j&3)
    const int jt  = w * 128 + l31;
    const int fb0 = jt * 64 + (((h    ) ^ (lane & 3)) << 4);
    const int fb1 = jt * 64 + (((h + 2) ^ (lane & 3)) << 4);

#define STAGE(t)                                                                      \
    do {                                                                              \
        __syncthreads();                                                              \
        const char* s_ = ksrc + (t) * 65536;                                          \
        _Pragma("unroll")                                                             \
        for (int o_ = 0; o_ < 8; ++o_)                                                \
            *reinterpret_cast<float4*>(kdst + o_ * 1024) =                            \
                *reinterpret_cast<const float4*>(s_ + o_ * 1024);                     \
        __syncthreads();                                                              \
    } while (0)

    // ---------------- pass A: row max ----------------
    float m16[16];
    #pragma unroll
    for (int q = 0; q < 16; ++q) m16[q] = -3.0e38f;

    for (int t = 0; t < 4; ++t) {
        STAGE(t);
        #pragma unroll
        for (int s = 0; s < 4; ++s) {
            const int off = s * 2048;
            bf16x8 b0 = *reinterpret_cast<const bf16x8*>(ktc + fb0 + off);
            bf16x8 b1 = *reinterpret_cast<const bf16x8*>(ktc + fb1 + off);
            f32x16 acc{};
            acc = __builtin_amdgcn_mfma_f32_32x32x16_bf16(a0, b0, acc, 0, 0, 0);
            acc = __builtin_amdgcn_mfma_f32_32x32x16_bf16(a1, b1, acc, 0, 0, 0);
            #pragma unroll
            for (int q = 0; q < 16; ++q) m16[q] = fmaxf(m16[q], acc[q]);
        }
    }
    #pragma unroll
    for (int q = 0; q < 16; ++q) {
        float v = m16[q];
        v = fmaxf(v, __shfl_xor(v, 1, 64));
        v = fmaxf(v, __shfl_xor(v, 2, 64));
        v = fmaxf(v, __shfl_xor(v, 4, 64));
        v = fmaxf(v, __shfl_xor(v, 8, 64));
        v = fmaxf(v, __shfl_xor(v, 16, 64));
        if (l31 == 0) red[w][(q & 3) + 8 * (q >> 2) + 4 * h] = v;
    }
    __syncthreads();
    if (tid < 32) {
        float v = red[0][tid];
        #pragma unroll
        for (int ww = 1; ww < 8; ++ww) v = fmaxf(v, red[ww][tid]);
        rowv[tid] = v;
    }
    __syncthreads();
    float mr[16];
    #pragma unroll
    for (int q = 0; q < 16; ++q) mr[q] = rowv[(q & 3) + 8 * (q >> 2) + 4 * h];

    // ---------------- pass B: row sum of exp ----------------
    float s16[16];
    #pragma unroll
    for (int q = 0; q < 16; ++q) s16[q] = 0.f;

    for (int t = 0; t < 4; ++t) {
        STAGE(t);
        #pragma unroll
        for (int s = 0; s < 4; ++s) {
            const int off = s * 2048;
            bf16x8 b0 = *reinterpret_cast<const bf16x8*>(ktc + fb0 + off);
            bf16x8 b1 = *reinterpret_cast<const bf16x8*>(ktc + fb1 + off);
            f32x16 acc{};
            acc = __builtin_amdgcn_mfma_f32_32x32x16_bf16(a0, b0, acc, 0, 0, 0);
            acc = __builtin_amdgcn_mfma_f32_32x32x16_bf16(a1, b1, acc, 0, 0, 0);
            #pragma unroll
            for (int q = 0; q < 16; ++q) s16[q] += __expf(acc[q] - mr[q]);
        }
    }
    #pragma unroll
    for (int q = 0; q < 16; ++q) {
        float v = s16[q];
        v += __shfl_xor(v, 1, 64);
        v += __shfl_xor(v, 2, 64);
        v += __shfl_xor(v, 4, 64);
        v += __shfl_xor(v, 8, 64);
        v += __shfl_xor(v, 16, 64);
        if (l31 == 0) red[w][(q & 3) + 8 * (q >> 2) + 4 * h] = v;
    }
    __syncthreads();
    if (tid < 32) {
        float v = red[0][tid];
        #pragma unroll
        for (int ww = 1; ww < 8; ++ww) v += red[ww][tid];
        rowv[tid] = 1.0f / v;
    }
    __syncthreads();
    float is[16];
    #pragma unroll
    for (int q = 0; q < 16; ++q) is[q] = rowv[(q & 3) + 8 * (q >> 2) + 4 * h];

    // ---------------- pass C: normalize + write ----------------
    for (int t = 0; t < 4; ++t) {
        STAGE(t);
        #pragma unroll
        for (int s = 0; s < 4; ++s) {
            const int off = s * 2048;
            bf16x8 b0 = *reinterpret_cast<const bf16x8*>(ktc + fb0 + off);
            bf16x8 b1 = *reinterpret_cast<const bf16x8*>(ktc + fb1 + off);
            f32x16 acc{};
            acc = __builtin_amdgcn_mfma_f32_32x32x16_bf16(a0, b0, acc, 0, 0, 0);
            acc = __builtin_amdgcn_mfma_f32_32x32x16_bf16(a1, b1, acc, 0, 0, 0);
            const int j = t * 1024 + w * 128 + s * 32 + l31;
            float* ab = att + ((size_t)b * NN + i0 + 4 * h) * NN + j;
            #pragma unroll
            for (int q = 0; q < 16; ++q)
                ab[(size_t)((q & 3) + 8 * (q >> 2)) * NN] = __expf(acc[q] - mr[q]) * is[q];
        }
    }
#undef STAGE
}

// ---------------------------------------------------------------------------
// K4: PV (gamma-guarded; never runs when gamma==0)
// ---------------------------------------------------------------------------
__global__ __launch_bounds__(256) void pv_kernel(
    const float* __restrict__ att, const float* __restrict__ Vt,
    const float* __restrict__ gamma, float* __restrict__ Pt)
{
    if (gamma[0] == 0.f) return;
    const size_t idx = (size_t)blockIdx.x * 256 + threadIdx.x;  // over B*N*C
    const int c = (int)(idx % CC);
    const size_t bn = idx / CC;
    const int i = (int)(bn % NN);
    const int b = (int)(bn / NN);

    const float* arow = att + ((size_t)b * NN + i) * NN;
    const float* vcol = Vt + (size_t)b * NN * CC + c;
    float acc = 0.f;
    for (int j = 0; j < NN; ++j) acc += arow[j] * vcol[(size_t)j * CC];
    Pt[idx] = acc;
}

// ---------------------------------------------------------------------------
// K5: out = gamma * PV + x   (gamma==0 -> exact copy of x)
// ---------------------------------------------------------------------------
__global__ __launch_bounds__(256) void out_kernel(
    const float* __restrict__ x, const float* __restrict__ Pt,
    const float* __restrict__ gamma, float* __restrict__ out)
{
    const size_t idx = (size_t)blockIdx.x * 256 + threadIdx.x;  // over B*C*N
    const float g = gamma[0];
    float v = x[idx];
    if (g != 0.f) {
        const int n = (int)(idx % NN);
        const size_t bc = idx / NN;
        const int c = (int)(bc % CC);
        const int b = (int)(bc / CC);
        v += g * Pt[((size_t)b * NN + n) * CC + c];
    }
    out[idx] = v;
}

extern "C" void kernel_launch(void* const* d_in, const int* in_sizes, int n_in,
                              void* d_out, int out_size, void* d_ws, size_t ws_size,
                              hipStream_t stream)
{
    const float* x     = (const float*)d_in[0];
    const float* wq    = (const float*)d_in[1];
    const float* bq    = (const float*)d_in[2];
    const float* wk    = (const float*)d_in[3];
    const float* bk    = (const float*)d_in[4];
    const float* wv    = (const float*)d_in[5];
    const float* bv    = (const float*)d_in[6];
    const float* gamma = (const float*)d_in[7];

    float* out = (float*)d_out;                    // [B,C,W,H]
    float* att = out + (size_t)BB * CC * NN;       // [B,N,N]

    unsigned short* Qtb = (unsigned short*)d_ws;             // B*N*CQ bf16 (1 MB)
    unsigned short* Ktb = Qtb + (size_t)BB * NN * CQ;        // 1 MB (swizzled)
    float* Vt = (float*)(Ktb + (size_t)BB * NN * CQ);        // B*N*C f32
    float* Pt = Vt + (size_t)BB * NN * CC;

    qk_proj_kernel<<<dim3(NN / 128, 4, BB), 128, 0, stream>>>(x, wq, bq, wk, bk, Qtb, Ktb);
    v_proj_kernel<<<dim3(NN / 256, CC / 8, BB), 256, 0, stream>>>(x, wv, bv, gamma, Vt);
    attn_kernel<<<dim3(NN / 32, BB), 512, 0, stream>>>(Qtb, Ktb, att);
    pv_kernel<<<dim3((BB * NN * CC) / 256), 256, 0, stream>>>(att, Vt, gamma, Pt);
    out_kernel<<<dim3((BB * CC * NN) / 256), 256, 0, stream>>>(x, Pt, gamma, out);
}

// Round 3
// 121.069 us; speedup vs baseline: 2.0888x; 1.1581x over previous
//
#include <hip/hip_runtime.h>

#define BB 4
#define CC 256
#define CQ 32
#define NN 4096   // 64*64

typedef __attribute__((ext_vector_type(8))) short bf16x8;
typedef __attribute__((ext_vector_type(16))) float f32x16;

__device__ __forceinline__ unsigned short f2bf(float f) {
    unsigned int u = __float_as_uint(f);
    unsigned int r = (u + 0x7fffu + ((u >> 16) & 1u)) >> 16;
    return (unsigned short)r;
}

// ---------------------------------------------------------------------------
// K1: Q/K projections -> transposed bf16 buffers [b][n][cq] (linear, no swizzle)
// grid (NN/128, 4, BB), block 128. grp 0,1 = Q halves; 2,3 = K halves.
// ---------------------------------------------------------------------------
__global__ __launch_bounds__(128) void qk_proj_kernel(
    const float* __restrict__ x,
    const float* __restrict__ wq, const float* __restrict__ bq,
    const float* __restrict__ wk, const float* __restrict__ bk,
    unsigned short* __restrict__ Qtb, unsigned short* __restrict__ Ktb)
{
    const int n   = blockIdx.x * 128 + threadIdx.x;
    const int grp = blockIdx.y;
    const int b   = blockIdx.z;
    const bool isQ = (grp < 2);
    const int o0 = (grp & 1) * 16;

    const float* w    = isQ ? wq : wk;
    const float* bias = isQ ? bq : bk;

    float acc[16];
    #pragma unroll
    for (int u = 0; u < 16; ++u) acc[u] = bias[o0 + u];

    const float* xp = x + (size_t)b * CC * NN + n;
    const float* wp = w + (size_t)o0 * CC;
    #pragma unroll 4
    for (int c = 0; c < CC; ++c) {
        float xv = xp[(size_t)c * NN];
        #pragma unroll
        for (int u = 0; u < 16; ++u) acc[u] += wp[u * CC + c] * xv;
    }

    unsigned int pk[8];
    #pragma unroll
    for (int j = 0; j < 8; ++j)
        pk[j] = (unsigned int)f2bf(acc[2 * j]) | ((unsigned int)f2bf(acc[2 * j + 1]) << 16);
    uint4 lo = make_uint4(pk[0], pk[1], pk[2], pk[3]);
    uint4 hi = make_uint4(pk[4], pk[5], pk[6], pk[7]);

    unsigned short* dst = (isQ ? Qtb : Ktb) + ((size_t)b * NN + n) * CQ;
    *reinterpret_cast<uint4*>(dst + o0)     = lo;
    *reinterpret_cast<uint4*>(dst + o0 + 8) = hi;
}

// ---------------------------------------------------------------------------
// K2: V projection -> Vt[b][n][c]  (gamma-guarded; skipped when gamma==0)
// ---------------------------------------------------------------------------
__global__ __launch_bounds__(256) void v_proj_kernel(
    const float* __restrict__ x,
    const float* __restrict__ wv, const float* __restrict__ bv,
    const float* __restrict__ gamma,
    float* __restrict__ Vt)
{
    if (gamma[0] == 0.f) return;
    const int n  = blockIdx.x * 256 + threadIdx.x;
    const int c0 = blockIdx.y * 8;
    const int b  = blockIdx.z;

    const float* wr[8];
    float bb2[8];
    #pragma unroll
    for (int u = 0; u < 8; ++u) { wr[u] = wv + (size_t)(c0 + u) * CC; bb2[u] = bv[c0 + u]; }

    float acc[8];
    #pragma unroll
    for (int u = 0; u < 8; ++u) acc[u] = 0.f;

    const float* xp = x + (size_t)b * CC * NN + n;
    #pragma unroll 4
    for (int c = 0; c < CC; ++c) {
        float xv = xp[(size_t)c * NN];
        #pragma unroll
        for (int u = 0; u < 8; ++u) acc[u] += wr[u][c] * xv;
    }
    #pragma unroll
    for (int u = 0; u < 8; ++u)
        Vt[((size_t)b * NN + n) * CC + c0 + u] = acc[u] + bb2[u];
}

// ---------------------------------------------------------------------------
// K3: MFMA energy + 2-pass softmax (online m/s, then normalize+write).
// Block = 32 query rows x 4096 cols, 8 waves. Wave w owns cols [w*512, w*512+512).
// No LDS staging: K-batch (256 KB) is L2-resident; B-frags read from global.
// C-frag layout (m101-verified): col=lane&31, row=(reg&3)+8*(reg>>2)+4*(lane>>5)
// ---------------------------------------------------------------------------
__global__ __launch_bounds__(512, 4) void attn_kernel(
    const unsigned short* __restrict__ Qtb,
    const unsigned short* __restrict__ Ktb,
    float* __restrict__ att)
{
    __shared__ float red_m[8][32];
    __shared__ float red_s[8][32];
    __shared__ float rowm[32];
    __shared__ float rowis[32];

    const int tid  = threadIdx.x;
    const int w    = tid >> 6;
    const int lane = tid & 63;
    const int l31  = lane & 31;
    const int h    = lane >> 5;
    const int b    = blockIdx.y;
    const int i0   = blockIdx.x * 32;

    // A-frags: Q rows i0..i0+31; lane: row=l31, k-chunks h and h+2 (8 cq each)
    const unsigned short* qb = Qtb + ((size_t)b * NN + i0 + l31) * CQ;
    const bf16x8 a0 = *reinterpret_cast<const bf16x8*>(qb + h * 8);
    const bf16x8 a1 = *reinterpret_cast<const bf16x8*>(qb + (h + 2) * 8);

    // B-frags: col j = w*512 + u*32 + l31, k-chunks h and h+2
    const unsigned short* kf = Ktb + ((size_t)b * NN + w * 512 + l31) * CQ;

    // ---------------- pass 1: energy + online (m, s) ----------------
    float m16[16], s16[16];
    #pragma unroll
    for (int q = 0; q < 16; ++q) { m16[q] = -3.0e38f; s16[q] = 0.f; }

    for (int u = 0; u < 16; ++u) {
        const unsigned short* kp = kf + (size_t)u * 32 * CQ;
        bf16x8 b0 = *reinterpret_cast<const bf16x8*>(kp + h * 8);
        bf16x8 b1 = *reinterpret_cast<const bf16x8*>(kp + (h + 2) * 8);
        f32x16 acc{};
        acc = __builtin_amdgcn_mfma_f32_32x32x16_bf16(a0, b0, acc, 0, 0, 0);
        acc = __builtin_amdgcn_mfma_f32_32x32x16_bf16(a1, b1, acc, 0, 0, 0);
        #pragma unroll
        for (int q = 0; q < 16; ++q) {
            float v  = acc[q];
            float mN = fmaxf(m16[q], v);
            s16[q] = s16[q] * __expf(m16[q] - mN) + __expf(v - mN);
            m16[q] = mN;
        }
    }

    // cross-lane merge over the 32 cols held by l31 peers
    #pragma unroll
    for (int q = 0; q < 16; ++q) {
        float m = m16[q], s = s16[q];
        #pragma unroll
        for (int d = 1; d <= 16; d <<= 1) {
            float m2 = __shfl_xor(m, d, 64);
            float s2 = __shfl_xor(s, d, 64);
            float mN = fmaxf(m, m2);
            s = s * __expf(m - mN) + s2 * __expf(m2 - mN);
            m = mN;
        }
        if (l31 == 0) {
            int r = (q & 3) + 8 * (q >> 2) + 4 * h;
            red_m[w][r] = m;
            red_s[w][r] = s;
        }
    }
    __syncthreads();
    if (tid < 32) {
        float m = red_m[0][tid], s = red_s[0][tid];
        #pragma unroll
        for (int ww = 1; ww < 8; ++ww) {
            float m2 = red_m[ww][tid], s2 = red_s[ww][tid];
            float mN = fmaxf(m, m2);
            s = s * __expf(m - mN) + s2 * __expf(m2 - mN);
            m = mN;
        }
        rowm[tid]  = m;
        rowis[tid] = 1.0f / s;
    }
    __syncthreads();

    float mr[16], is[16];
    #pragma unroll
    for (int q = 0; q < 16; ++q) {
        int r = (q & 3) + 8 * (q >> 2) + 4 * h;
        mr[q] = rowm[r];
        is[q] = rowis[r];
    }

    // ---------------- pass 2: recompute energy, normalize, write ----------------
    for (int u = 0; u < 16; ++u) {
        const unsigned short* kp = kf + (size_t)u * 32 * CQ;
        bf16x8 b0 = *reinterpret_cast<const bf16x8*>(kp + h * 8);
        bf16x8 b1 = *reinterpret_cast<const bf16x8*>(kp + (h + 2) * 8);
        f32x16 acc{};
        acc = __builtin_amdgcn_mfma_f32_32x32x16_bf16(a0, b0, acc, 0, 0, 0);
        acc = __builtin_amdgcn_mfma_f32_32x32x16_bf16(a1, b1, acc, 0, 0, 0);
        const int j = w * 512 + u * 32 + l31;
        float* ab = att + ((size_t)b * NN + i0 + 4 * h) * NN + j;
        #pragma unroll
        for (int q = 0; q < 16; ++q)
            __builtin_nontemporal_store(__expf(acc[q] - mr[q]) * is[q],
                                        &ab[(size_t)((q & 3) + 8 * (q >> 2)) * NN]);
    }
}

// ---------------------------------------------------------------------------
// K4: PV (gamma-guarded; never runs when gamma==0)
// ---------------------------------------------------------------------------
__global__ __launch_bounds__(256) void pv_kernel(
    const float* __restrict__ att, const float* __restrict__ Vt,
    const float* __restrict__ gamma, float* __restrict__ Pt)
{
    if (gamma[0] == 0.f) return;
    const size_t idx = (size_t)blockIdx.x * 256 + threadIdx.x;  // over B*N*C
    const int c = (int)(idx % CC);
    const size_t bn = idx / CC;
    const int i = (int)(bn % NN);
    const int b = (int)(bn / NN);

    const float* arow = att + ((size_t)b * NN + i) * NN;
    const float* vcol = Vt + (size_t)b * NN * CC + c;
    float acc = 0.f;
    for (int j = 0; j < NN; ++j) acc += arow[j] * vcol[(size_t)j * CC];
    Pt[idx] = acc;
}

// ---------------------------------------------------------------------------
// K5: out = gamma * PV + x   (gamma==0 -> exact copy of x), float4
// ---------------------------------------------------------------------------
__global__ __launch_bounds__(256) void out_kernel(
    const float* __restrict__ x, const float* __restrict__ Pt,
    const float* __restrict__ gamma, float* __restrict__ out)
{
    const size_t i4 = ((size_t)blockIdx.x * 256 + threadIdx.x) * 4;  // over B*C*N
    const float g = gamma[0];
    float4 v = *reinterpret_cast<const float4*>(x + i4);
    if (g != 0.f) {
        #pragma unroll
        for (int e = 0; e < 4; ++e) {
            const size_t idx = i4 + e;
            const int n = (int)(idx % NN);
            const size_t bc = idx / NN;
            const int c = (int)(bc % CC);
            const int bb = (int)(bc / CC);
            float p = Pt[((size_t)bb * NN + n) * CC + c];
            (&v.x)[e] += g * p;
        }
    }
    *reinterpret_cast<float4*>(out + i4) = v;
}

extern "C" void kernel_launch(void* const* d_in, const int* in_sizes, int n_in,
                              void* d_out, int out_size, void* d_ws, size_t ws_size,
                              hipStream_t stream)
{
    const float* x     = (const float*)d_in[0];
    const float* wq    = (const float*)d_in[1];
    const float* bq    = (const float*)d_in[2];
    const float* wk    = (const float*)d_in[3];
    const float* bk    = (const float*)d_in[4];
    const float* wv    = (const float*)d_in[5];
    const float* bv    = (const float*)d_in[6];
    const float* gamma = (const float*)d_in[7];

    float* out = (float*)d_out;                    // [B,C,W,H]
    float* att = out + (size_t)BB * CC * NN;       // [B,N,N]

    unsigned short* Qtb = (unsigned short*)d_ws;             // B*N*CQ bf16 (1 MB)
    unsigned short* Ktb = Qtb + (size_t)BB * NN * CQ;        // 1 MB
    float* Vt = (float*)(Ktb + (size_t)BB * NN * CQ);        // B*N*C f32
    float* Pt = Vt + (size_t)BB * NN * CC;

    qk_proj_kernel<<<dim3(NN / 128, 4, BB), 128, 0, stream>>>(x, wq, bq, wk, bk, Qtb, Ktb);
    v_proj_kernel<<<dim3(NN / 256, CC / 8, BB), 256, 0, stream>>>(x, wv, bv, gamma, Vt);
    attn_kernel<<<dim3(NN / 32, BB), 512, 0, stream>>>(Qtb, Ktb, att);
    pv_kernel<<<dim3((BB * NN * CC) / 256), 256, 0, stream>>>(att, Vt, gamma, Pt);
    out_kernel<<<dim3((BB * CC * NN) / 1024), 256, 0, stream>>>(x, Pt, gamma, out);
}